// Round 2
// baseline (1063.286 us; speedup 1.0000x reference)
//
#include <hip/hip_runtime.h>
#include <hip/hip_bf16.h>
#include <math.h>

// Problem constants: B=2, T=2048, C=1024, H=16, D=64, N=2C=2048
#define BB 2
#define TT 2048
#define CC 1024
#define HH 16
#define DD 64

// ---------------------------------------------------------------------------
// Kernel 1: qk[m][n] = sum_k x[m][k] * W[k][n] + bias[n]
//   M = B*T = 4096, N = 2C = 2048, K = C = 1024. fp32 in/out.
//   64x64 tile, BK=16, 256 threads, 4x4 micro-tile per thread.
// ---------------------------------------------------------------------------
__global__ __launch_bounds__(256) void gemm_qk_kernel(
    const float* __restrict__ X,
    const float* __restrict__ W,
    const float* __restrict__ bias,
    float* __restrict__ QK,
    int M, int N, int K)
{
    __shared__ float As[16][64 + 1];  // [k][m], padded
    __shared__ float Bs[16][64];      // [k][n]

    const int tid = threadIdx.x;
    const int tx = tid & 15;          // 0..15 -> n micro
    const int ty = tid >> 4;          // 0..15 -> m micro
    const int m0 = blockIdx.y * 64;
    const int n0 = blockIdx.x * 64;

    float acc[4][4] = {};

    for (int k0 = 0; k0 < K; k0 += 16) {
        // Load A tile: 64 rows x 16 k-cols (1024 elems, 4 per thread)
        {
            const int col = tid & 15;        // k within tile
            const int rbase = tid >> 4;      // 0..15
            #pragma unroll
            for (int p = 0; p < 4; ++p) {
                const int row = rbase + p * 16;   // 0..63
                As[col][row] = X[(size_t)(m0 + row) * K + k0 + col];
            }
        }
        // Load B tile: 16 k-rows x 64 n-cols
        {
            const int col = tid & 63;
            const int rbase = tid >> 6;      // 0..3
            #pragma unroll
            for (int p = 0; p < 4; ++p) {
                const int row = rbase + p * 4;    // 0..15
                Bs[row][col] = W[(size_t)(k0 + row) * N + n0 + col];
            }
        }
        __syncthreads();

        #pragma unroll
        for (int kk = 0; kk < 16; ++kk) {
            float a[4], b[4];
            #pragma unroll
            for (int i = 0; i < 4; ++i) a[i] = As[kk][ty * 4 + i];
            #pragma unroll
            for (int j = 0; j < 4; ++j) b[j] = Bs[kk][tx * 4 + j];
            #pragma unroll
            for (int i = 0; i < 4; ++i)
                #pragma unroll
                for (int j = 0; j < 4; ++j)
                    acc[i][j] += a[i] * b[j];
        }
        __syncthreads();
    }

    #pragma unroll
    for (int i = 0; i < 4; ++i) {
        const int m = m0 + ty * 4 + i;
        #pragma unroll
        for (int j = 0; j < 4; ++j) {
            const int n = n0 + tx * 4 + j;
            QK[(size_t)m * N + n] = acc[i][j] + bias[n];
        }
    }
}

// ---------------------------------------------------------------------------
// Kernel 2: causal flash attention.
//   Q from QK[..., :C], K from QK[..., C:], V from xt (fp32, reshaped).
//   Block = 256 threads; grid = (T/64, B*H).
//   Each block: 64 query rows for one (b,h). Online softmax, fp32 throughout.
// ---------------------------------------------------------------------------
__global__ __launch_bounds__(256) void attn_kernel(
    const float* __restrict__ QK,
    const float* __restrict__ XV,
    float* __restrict__ Y)
{
    const int N2 = 2 * CC;
    const int bh = blockIdx.y;
    const int b = bh / HH;
    const int h = bh % HH;
    const int qt = blockIdx.x;
    const int q0 = qt * 64;

    const int tid = threadIdx.x;
    const int tx = tid & 15;   // key / dim micro index
    const int ty = tid >> 4;   // query-row micro index

    __shared__ float Qs[64][65];
    __shared__ float Ks[64][65];
    __shared__ float Vs[64][65];
    __shared__ float Ps[64][65];

    // Load Q tile: rows q0..q0+63, dims h*64..h*64+63
    {
        const int col = tid & 63;
        const int r4 = tid >> 6;     // 0..3
        #pragma unroll
        for (int p = 0; p < 16; ++p) {
            const int row = (p << 2) + r4;
            Qs[row][col] = QK[(size_t)(b * TT + q0 + row) * N2 + h * DD + col];
        }
    }

    float o[4][4] = {};
    float mrow[4] = {-INFINITY, -INFINITY, -INFINITY, -INFINITY};
    float lrow[4] = {0.f, 0.f, 0.f, 0.f};
    const float scale = 0.125f;  // 1/sqrt(64)

    for (int kt = 0; kt <= qt; ++kt) {
        const int k0 = kt * 64;
        __syncthreads();  // protect Ks/Vs (prev S read) and Ps (prev PV read)
        // Load K tile and V tile
        {
            const int col = tid & 63;
            const int r4 = tid >> 6;
            #pragma unroll
            for (int p = 0; p < 16; ++p) {
                const int row = (p << 2) + r4;
                Ks[row][col] =
                    QK[(size_t)(b * TT + k0 + row) * N2 + CC + h * DD + col];
                Vs[row][col] = XV[(size_t)(b * TT + k0 + row) * CC + h * DD + col];
            }
        }
        __syncthreads();

        // S = Q K^T (this thread: rows ty*4.., keys tx*4..)
        float s[4][4] = {};
        #pragma unroll 8
        for (int d = 0; d < 64; ++d) {
            float a[4], bb[4];
            #pragma unroll
            for (int i = 0; i < 4; ++i) a[i] = Qs[ty * 4 + i][d];
            #pragma unroll
            for (int j = 0; j < 4; ++j) bb[j] = Ks[tx * 4 + j][d];
            #pragma unroll
            for (int i = 0; i < 4; ++i)
                #pragma unroll
                for (int j = 0; j < 4; ++j)
                    s[i][j] += a[i] * bb[j];
        }

        // scale + causal mask (only the diagonal tile needs masking)
        const bool diag = (kt == qt);
        #pragma unroll
        for (int i = 0; i < 4; ++i) {
            const int qi = q0 + ty * 4 + i;
            #pragma unroll
            for (int j = 0; j < 4; ++j) {
                const int kj = k0 + tx * 4 + j;
                const float v = s[i][j] * scale;
                s[i][j] = (!diag || kj <= qi) ? v : -INFINITY;
            }
        }

        // online softmax per row (16 lanes own each row)
        float alpha[4];
        #pragma unroll
        for (int i = 0; i < 4; ++i) {
            float mloc = fmaxf(fmaxf(s[i][0], s[i][1]),
                               fmaxf(s[i][2], s[i][3]));
            #pragma unroll
            for (int off = 1; off < 16; off <<= 1)
                mloc = fmaxf(mloc, __shfl_xor(mloc, off, 16));
            const float mnew = fmaxf(mrow[i], mloc);
            alpha[i] = __expf(mrow[i] - mnew);  // exp(-inf)=0 on first tile
            mrow[i] = mnew;
            float psum = 0.f;
            #pragma unroll
            for (int j = 0; j < 4; ++j) {
                const float p = __expf(s[i][j] - mnew);
                s[i][j] = p;
                psum += p;
            }
            #pragma unroll
            for (int off = 1; off < 16; off <<= 1)
                psum += __shfl_xor(psum, off, 16);
            lrow[i] = lrow[i] * alpha[i] + psum;
        }

        // stage P in LDS (safe: last Ps read was before this iter's 1st sync)
        #pragma unroll
        for (int i = 0; i < 4; ++i)
            #pragma unroll
            for (int j = 0; j < 4; ++j)
                Ps[ty * 4 + i][tx * 4 + j] = s[i][j];
        __syncthreads();

        // O = O*alpha + P @ V   (this thread: rows ty*4.., dims tx*4..)
        #pragma unroll
        for (int i = 0; i < 4; ++i)
            #pragma unroll
            for (int j = 0; j < 4; ++j)
                o[i][j] *= alpha[i];
        #pragma unroll 8
        for (int kk = 0; kk < 64; ++kk) {
            float p[4], vv[4];
            #pragma unroll
            for (int i = 0; i < 4; ++i) p[i] = Ps[ty * 4 + i][kk];
            #pragma unroll
            for (int j = 0; j < 4; ++j) vv[j] = Vs[kk][tx * 4 + j];
            #pragma unroll
            for (int i = 0; i < 4; ++i)
                #pragma unroll
                for (int j = 0; j < 4; ++j)
                    o[i][j] += p[i] * vv[j];
        }
    }

    // epilogue: divide by l, write fp32 output y[b][t][h*64+d]
    #pragma unroll
    for (int i = 0; i < 4; ++i) {
        const int t = q0 + ty * 4 + i;
        const float inv_l = 1.0f / lrow[i];
        #pragma unroll
        for (int j = 0; j < 4; ++j) {
            const int d = tx * 4 + j;
            Y[(size_t)(b * TT + t) * CC + h * DD + d] = o[i][j] * inv_l;
        }
    }
}

// ---------------------------------------------------------------------------
extern "C" void kernel_launch(void* const* d_in, const int* in_sizes, int n_in,
                              void* d_out, int out_size, void* d_ws,
                              size_t ws_size, hipStream_t stream)
{
    const float* x_qk = (const float*)d_in[0];
    const float* x_v  = (const float*)d_in[1];
    const float* W    = (const float*)d_in[2];
    const float* bias = (const float*)d_in[3];
    float* out = (float*)d_out;

    float* qk_ws = (float*)d_ws;  // M x N fp32 = 4096*2048*4 = 33.5 MB

    const int M = BB * TT;   // 4096
    const int N = 2 * CC;    // 2048
    const int K = CC;        // 1024

    dim3 ggrid(N / 64, M / 64);  // (32, 64)
    gemm_qk_kernel<<<ggrid, 256, 0, stream>>>(x_qk, W, bias, qk_ws, M, N, K);

    dim3 agrid(TT / 64, BB * HH);  // (32, 32)
    attn_kernel<<<agrid, 256, 0, stream>>>(qk_ws, x_v, out);
}

// Round 3
// 254.380 us; speedup vs baseline: 4.1799x; 4.1799x over previous
//
#include <hip/hip_runtime.h>
#include <hip/hip_bf16.h>
#include <math.h>

// B=2, T=2048, C=1024, H=16, D=64, N=2C=2048
#define BB 2
#define TT 2048
#define CC 1024
#define HH 16
#define DD 64

typedef __attribute__((ext_vector_type(8))) short s8v;   // 8 bf16 (A/B frag)
typedef __attribute__((ext_vector_type(4))) float f4v;   // 4 fp32 (C/D frag)
typedef unsigned short ush;

// round-to-nearest-even fp32 -> bf16 bits
static __device__ __forceinline__ ush f2bf(float f) {
    unsigned int x = __builtin_bit_cast(unsigned int, f);
    unsigned int r = (x + 0x7fffu + ((x >> 16) & 1u)) >> 16;
    return (ush)r;
}

// ---------------------------------------------------------------------------
// Pre-pass 1: Wt[n][k] (bf16) = W[k][n] (fp32).  grid (N/64, K/64), 256 thr.
// ---------------------------------------------------------------------------
__global__ __launch_bounds__(256) void wt_kernel(
    const float* __restrict__ W, ush* __restrict__ Wt)
{
    __shared__ float Ts[64][68];
    const int tid = threadIdx.x;
    const int n0 = blockIdx.x * 64;
    const int k0 = blockIdx.y * 64;
    #pragma unroll
    for (int p = 0; p < 4; ++p) {
        const int idx = p * 256 + tid;
        const int kr = idx >> 4, nc4 = idx & 15;
        float4 v = *(const float4*)(W + (size_t)(k0 + kr) * 2048 + n0 + nc4 * 4);
        Ts[kr][nc4 * 4 + 0] = v.x; Ts[kr][nc4 * 4 + 1] = v.y;
        Ts[kr][nc4 * 4 + 2] = v.z; Ts[kr][nc4 * 4 + 3] = v.w;
    }
    __syncthreads();
    const int n = tid >> 2, kb = (tid & 3) * 16;
    #pragma unroll
    for (int p = 0; p < 4; ++p) {
        const int k = kb + p * 4;
        ushort4 o;
        o.x = f2bf(Ts[k + 0][n]); o.y = f2bf(Ts[k + 1][n]);
        o.z = f2bf(Ts[k + 2][n]); o.w = f2bf(Ts[k + 3][n]);
        *(ushort4*)(Wt + (size_t)(n0 + n) * 1024 + k0 + k) = o;
    }
}

// ---------------------------------------------------------------------------
// Pre-pass 2: Vt[b][h][d][t] (bf16) = x_v[b][t][h*64+d].  grid (T/64, B*H).
// ---------------------------------------------------------------------------
__global__ __launch_bounds__(256) void vt_kernel(
    const float* __restrict__ XV, ush* __restrict__ Vt)
{
    __shared__ float Ts[64][68];
    const int tid = threadIdx.x;
    const int t0 = blockIdx.x * 64;
    const int bh = blockIdx.y;
    const int b = bh >> 4, h = bh & 15;
    #pragma unroll
    for (int p = 0; p < 4; ++p) {
        const int idx = p * 256 + tid;
        const int tr = idx >> 4, dc4 = idx & 15;
        float4 v = *(const float4*)(XV + (size_t)(b * 2048 + t0 + tr) * 1024
                                    + h * 64 + dc4 * 4);
        Ts[tr][dc4 * 4 + 0] = v.x; Ts[tr][dc4 * 4 + 1] = v.y;
        Ts[tr][dc4 * 4 + 2] = v.z; Ts[tr][dc4 * 4 + 3] = v.w;
    }
    __syncthreads();
    const int d = tid >> 2, tb = (tid & 3) * 16;
    #pragma unroll
    for (int p = 0; p < 4; ++p) {
        const int tq = tb + p * 4;
        ushort4 o;
        o.x = f2bf(Ts[tq + 0][d]); o.y = f2bf(Ts[tq + 1][d]);
        o.z = f2bf(Ts[tq + 2][d]); o.w = f2bf(Ts[tq + 3][d]);
        *(ushort4*)(Vt + (size_t)((b * 16 + h) * 64 + d) * 2048 + t0 + tq) = o;
    }
}

// ---------------------------------------------------------------------------
// Kernel 3: MFMA GEMM  C = X(4096x1024) @ W(1024x2048) + bias
//   128x128 tile, BK=32, 4 waves (2x2), each wave 64x64 = 4x4 MFMA tiles.
//   Epilogue: +bias, ->bf16, write Q/K in [b][h][t][d].
// ---------------------------------------------------------------------------
__global__ __launch_bounds__(256) void gemm_kernel(
    const float* __restrict__ X, const ush* __restrict__ Wt,
    const float* __restrict__ bias,
    ush* __restrict__ Qb, ush* __restrict__ Kb)
{
    __shared__ ush As[128 * 40];   // [m][k], row stride 40 elems (80B)
    __shared__ ush Bs[128 * 40];   // [n][k]

    const int tid = threadIdx.x;
    const int wid = tid >> 6, lane = tid & 63;
    const int quad = lane >> 4, l15 = lane & 15;
    const int wm = wid >> 1, wn = wid & 1;
    const int m0 = blockIdx.y * 128, n0 = blockIdx.x * 128;

    f4v acc[4][4];
    #pragma unroll
    for (int i = 0; i < 4; ++i)
        #pragma unroll
        for (int j = 0; j < 4; ++j) acc[i][j] = (f4v){0.f, 0.f, 0.f, 0.f};

    for (int k0 = 0; k0 < 1024; k0 += 32) {
        // stage A: 128x32 fp32 -> bf16 LDS
        #pragma unroll
        for (int p = 0; p < 4; ++p) {
            const int idx = p * 256 + tid;
            const int row = idx >> 3, fq = idx & 7;
            float4 v = *(const float4*)(X + (size_t)(m0 + row) * 1024 + k0 + fq * 4);
            ushort4 o;
            o.x = f2bf(v.x); o.y = f2bf(v.y); o.z = f2bf(v.z); o.w = f2bf(v.w);
            *(ushort4*)&As[row * 40 + fq * 4] = o;
        }
        // stage B: Wt[n][k] bf16, 128 rows x 32 k
        #pragma unroll
        for (int p = 0; p < 2; ++p) {
            const int idx = p * 256 + tid;
            const int row = idx >> 2, c = idx & 3;
            uint4 v = *(const uint4*)(Wt + (size_t)(n0 + row) * 1024 + k0 + c * 8);
            *(uint4*)&Bs[row * 40 + c * 8] = v;
        }
        __syncthreads();

        s8v a[4], bfr[4];
        #pragma unroll
        for (int i = 0; i < 4; ++i)
            a[i] = *(const s8v*)&As[(wm * 64 + i * 16 + l15) * 40 + quad * 8];
        #pragma unroll
        for (int j = 0; j < 4; ++j)
            bfr[j] = *(const s8v*)&Bs[(wn * 64 + j * 16 + l15) * 40 + quad * 8];
        #pragma unroll
        for (int i = 0; i < 4; ++i)
            #pragma unroll
            for (int j = 0; j < 4; ++j)
                acc[i][j] = __builtin_amdgcn_mfma_f32_16x16x32_bf16(
                    a[i], bfr[j], acc[i][j], 0, 0, 0);
        __syncthreads();
    }

    // epilogue: C/D layout col=l15, row=quad*4+r
    #pragma unroll
    for (int j = 0; j < 4; ++j) {
        const int n = n0 + wn * 64 + j * 16 + l15;
        const float bv = bias[n];
        const bool is_k = n >= 1024;
        const int nn = n & 1023;
        const int h = nn >> 6, d = nn & 63;
        ush* dst = is_k ? Kb : Qb;
        #pragma unroll
        for (int i = 0; i < 4; ++i) {
            const int mrow = m0 + wm * 64 + i * 16 + quad * 4;
            #pragma unroll
            for (int r = 0; r < 4; ++r) {
                const int m = mrow + r;
                const int b = m >> 11, t = m & 2047;
                dst[(size_t)((b * 16 + h) * 2048 + t) * 64 + d] =
                    f2bf(acc[i][j][r] + bv);
            }
        }
    }
}

// ---------------------------------------------------------------------------
// Kernel 4: MFMA causal flash attention.
//   grid (T/64 reversed, B*H), 256 thr = 4 waves; wave w owns 16 query rows.
//   LDS rows padded to 72 elems (144B = 9x16B: aligned b128, 2-way conflicts).
// ---------------------------------------------------------------------------
__global__ __launch_bounds__(256) void attn_kernel(
    const ush* __restrict__ Qb, const ush* __restrict__ Kb,
    const ush* __restrict__ Vt, float* __restrict__ Y)
{
    __shared__ ush Qs[64 * 72];
    __shared__ ush Ks[64 * 72];
    __shared__ ush Vs[64 * 72];        // [d][key]
    __shared__ ush Ps[4][16 * 72];     // per-wave

    const int tid = threadIdx.x;
    const int w = tid >> 6, lane = tid & 63;
    const int quad = lane >> 4, l15 = lane & 15;
    const int bh = blockIdx.y;
    const int b = bh >> 4, h = bh & 15;
    const int qt = gridDim.x - 1 - blockIdx.x;   // heavy blocks first
    const int q0 = qt * 64;

    const ush* Qg = Qb + (size_t)(b * 16 + h) * 2048 * 64;
    const ush* Kg = Kb + (size_t)(b * 16 + h) * 2048 * 64;
    const ush* Vg = Vt + (size_t)(b * 16 + h) * 64 * 2048;

    // load Q tile: rows q0..q0+63 x 64 d (global-contiguous 8KB)
    #pragma unroll
    for (int p = 0; p < 2; ++p) {
        const int row = p * 32 + (tid >> 3), c = tid & 7;
        uint4 v = *(const uint4*)(Qg + (size_t)(q0 + row) * 64 + c * 8);
        *(uint4*)&Qs[row * 72 + c * 8] = v;
    }
    __syncthreads();

    s8v aq[2];
    #pragma unroll
    for (int s = 0; s < 2; ++s)
        aq[s] = *(const s8v*)&Qs[(w * 16 + l15) * 72 + s * 32 + quad * 8];

    f4v acco[4];
    #pragma unroll
    for (int e = 0; e < 4; ++e) acco[e] = (f4v){0.f, 0.f, 0.f, 0.f};
    float mr[4] = {-INFINITY, -INFINITY, -INFINITY, -INFINITY};
    float lr[4] = {0.f, 0.f, 0.f, 0.f};
    const float scale = 0.125f;

    for (int kt = 0; kt <= qt; ++kt) {
        const int k0 = kt * 64;
        __syncthreads();
        // stage K tile [key][d] (contiguous) and V tile [d][key]
        #pragma unroll
        for (int p = 0; p < 2; ++p) {
            const int row = p * 32 + (tid >> 3), c = tid & 7;
            uint4 kv = *(const uint4*)(Kg + (size_t)(k0 + row) * 64 + c * 8);
            *(uint4*)&Ks[row * 72 + c * 8] = kv;
            uint4 vv = *(const uint4*)(Vg + (size_t)row * 2048 + k0 + c * 8);
            *(uint4*)&Vs[row * 72 + c * 8] = vv;
        }
        __syncthreads();

        // S = Q K^T : 4 key-tiles x 2 k-steps
        f4v sacc[4];
        #pragma unroll
        for (int j = 0; j < 4; ++j) sacc[j] = (f4v){0.f, 0.f, 0.f, 0.f};
        #pragma unroll
        for (int s = 0; s < 2; ++s) {
            #pragma unroll
            for (int j = 0; j < 4; ++j) {
                s8v bk = *(const s8v*)&Ks[(j * 16 + l15) * 72 + s * 32 + quad * 8];
                sacc[j] = __builtin_amdgcn_mfma_f32_16x16x32_bf16(
                    aq[s], bk, sacc[j], 0, 0, 0);
            }
        }

        // scale + causal mask + online softmax (row = quad*4+r, col = j*16+l15)
        const bool diag = (kt == qt);
        #pragma unroll
        for (int r = 0; r < 4; ++r) {
            const int qg = q0 + w * 16 + quad * 4 + r;
            float sv[4];
            #pragma unroll
            for (int j = 0; j < 4; ++j) {
                float x = sacc[j][r] * scale;
                if (diag && (k0 + j * 16 + l15) > qg) x = -INFINITY;
                sv[j] = x;
            }
            float mloc = fmaxf(fmaxf(sv[0], sv[1]), fmaxf(sv[2], sv[3]));
            #pragma unroll
            for (int off = 1; off < 16; off <<= 1)
                mloc = fmaxf(mloc, __shfl_xor(mloc, off, 16));
            const float mnew = fmaxf(mr[r], mloc);
            const float alpha = __expf(mr[r] - mnew);
            mr[r] = mnew;
            float psum = 0.f;
            #pragma unroll
            for (int j = 0; j < 4; ++j) {
                const float p = __expf(sv[j] - mnew);
                Ps[w][(quad * 4 + r) * 72 + j * 16 + l15] = f2bf(p);
                psum += p;
            }
            #pragma unroll
            for (int off = 1; off < 16; off <<= 1)
                psum += __shfl_xor(psum, off, 16);
            lr[r] = lr[r] * alpha + psum;
            #pragma unroll
            for (int e = 0; e < 4; ++e) acco[e][r] *= alpha;
        }

        // O += P @ V  (P via wave-private LDS round-trip; in-order DS pipe)
        #pragma unroll
        for (int s = 0; s < 2; ++s) {
            s8v ap = *(const s8v*)&Ps[w][l15 * 72 + s * 32 + quad * 8];
            #pragma unroll
            for (int e = 0; e < 4; ++e) {
                s8v bv = *(const s8v*)&Vs[(e * 16 + l15) * 72 + s * 32 + quad * 8];
                acco[e] = __builtin_amdgcn_mfma_f32_16x16x32_bf16(
                    ap, bv, acco[e], 0, 0, 0);
            }
        }
    }

    // epilogue
    #pragma unroll
    for (int r = 0; r < 4; ++r) {
        const int q = q0 + w * 16 + quad * 4 + r;
        const float inv_l = 1.0f / lr[r];
        #pragma unroll
        for (int e = 0; e < 4; ++e) {
            const int d = e * 16 + l15;
            Y[(size_t)(b * 2048 + q) * 1024 + h * 64 + d] = acco[e][r] * inv_l;
        }
    }
}

// ---------------------------------------------------------------------------
extern "C" void kernel_launch(void* const* d_in, const int* in_sizes, int n_in,
                              void* d_out, int out_size, void* d_ws,
                              size_t ws_size, hipStream_t stream)
{
    const float* x_qk = (const float*)d_in[0];
    const float* x_v  = (const float*)d_in[1];
    const float* W    = (const float*)d_in[2];
    const float* bias = (const float*)d_in[3];
    float* out = (float*)d_out;

    unsigned char* ws = (unsigned char*)d_ws;
    ush* Wt = (ush*)(ws);                        //  4 MB
    ush* Qb = (ush*)(ws + (4u << 20));           //  8 MB
    ush* Kb = (ush*)(ws + (12u << 20));          //  8 MB
    ush* Vt = (ush*)(ws + (20u << 20));          //  8 MB  (28 MB total)

    wt_kernel<<<dim3(32, 16), 256, 0, stream>>>(W, Wt);
    vt_kernel<<<dim3(32, 32), 256, 0, stream>>>(x_v, Vt);
    gemm_kernel<<<dim3(16, 32), 256, 0, stream>>>(x_qk, Wt, bias, Qb, Kb);
    attn_kernel<<<dim3(32, 32), 256, 0, stream>>>(Qb, Kb, Vt, out);
}

// Round 4
// 166.590 us; speedup vs baseline: 6.3827x; 1.5270x over previous
//
#include <hip/hip_runtime.h>
#include <hip/hip_bf16.h>
#include <math.h>

// B=2, T=2048, C=1024, H=16, D=64
typedef __attribute__((ext_vector_type(8))) short s8v;   // 8 bf16 (A/B frag)
typedef __attribute__((ext_vector_type(4))) float f4v;   // 4 fp32 (C/D frag)
typedef unsigned short ush;
typedef unsigned int u32;

// fp32 -> bf16 (RNE)
static __device__ __forceinline__ ush f2bf(float f) {
    u32 x = __builtin_bit_cast(u32, f);
    return (ush)((x + 0x7fffu + ((x >> 16) & 1u)) >> 16);
}
// pack two fp32 -> (bf16 lo | bf16 hi<<16), round-half-up
static __device__ __forceinline__ u32 bfpack(float lo, float hi) {
    u32 a = __builtin_bit_cast(u32, lo) + 0x8000u;
    u32 b = __builtin_bit_cast(u32, hi) + 0x8000u;
    return __builtin_amdgcn_perm(b, a, 0x07060302);  // {b.hi16, a.hi16}
}
// async global->LDS, 16B per lane; lds base must be wave-uniform
static __device__ __forceinline__ void gl_lds16(const void* g, void* l) {
    __builtin_amdgcn_global_load_lds(
        (const __attribute__((address_space(1))) u32*)g,
        (__attribute__((address_space(3))) u32*)l, 16, 0, 0);
}

// ---------------------------------------------------------------------------
// Pre-pass: X fp32 -> bf16, straight copy. 4M elems, 8/thread.
// ---------------------------------------------------------------------------
__global__ __launch_bounds__(256) void xb_kernel(
    const float* __restrict__ X, ush* __restrict__ Xb)
{
    const size_t i = ((size_t)blockIdx.x * 256 + threadIdx.x) * 8;
    float4 v0 = *(const float4*)(X + i);
    float4 v1 = *(const float4*)(X + i + 4);
    uint4 o;
    o.x = bfpack(v0.x, v0.y); o.y = bfpack(v0.z, v0.w);
    o.z = bfpack(v1.x, v1.y); o.w = bfpack(v1.z, v1.w);
    *(uint4*)(Xb + i) = o;
}

// ---------------------------------------------------------------------------
// Pre-pass: Wt[n][k] (bf16) = W[k][n] (fp32).  grid (32, 16), 256 thr.
// ---------------------------------------------------------------------------
__global__ __launch_bounds__(256) void wt_kernel(
    const float* __restrict__ W, ush* __restrict__ Wt)
{
    __shared__ float Ts[64][68];
    const int tid = threadIdx.x;
    const int n0 = blockIdx.x * 64;
    const int k0 = blockIdx.y * 64;
    #pragma unroll
    for (int p = 0; p < 4; ++p) {
        const int idx = p * 256 + tid;
        const int kr = idx >> 4, nc4 = idx & 15;
        float4 v = *(const float4*)(W + (size_t)(k0 + kr) * 2048 + n0 + nc4 * 4);
        Ts[kr][nc4 * 4 + 0] = v.x; Ts[kr][nc4 * 4 + 1] = v.y;
        Ts[kr][nc4 * 4 + 2] = v.z; Ts[kr][nc4 * 4 + 3] = v.w;
    }
    __syncthreads();
    const int n = tid >> 2, kb = (tid & 3) * 16;
    #pragma unroll
    for (int p = 0; p < 4; ++p) {
        const int k = kb + p * 4;
        ushort4 o;
        o.x = f2bf(Ts[k + 0][n]); o.y = f2bf(Ts[k + 1][n]);
        o.z = f2bf(Ts[k + 2][n]); o.w = f2bf(Ts[k + 3][n]);
        *(ushort4*)(Wt + (size_t)(n0 + n) * 1024 + k0 + k) = o;
    }
}

// ---------------------------------------------------------------------------
// Pre-pass: Vt[b][h][d][t] (bf16) = x_v[b][t][h*64+d].  grid (32, 32).
// ---------------------------------------------------------------------------
__global__ __launch_bounds__(256) void vt_kernel(
    const float* __restrict__ XV, ush* __restrict__ Vt)
{
    __shared__ float Ts[64][68];
    const int tid = threadIdx.x;
    const int t0 = blockIdx.x * 64;
    const int bh = blockIdx.y;
    const int b = bh >> 4, h = bh & 15;
    #pragma unroll
    for (int p = 0; p < 4; ++p) {
        const int idx = p * 256 + tid;
        const int tr = idx >> 4, dc4 = idx & 15;
        float4 v = *(const float4*)(XV + (size_t)(b * 2048 + t0 + tr) * 1024
                                    + h * 64 + dc4 * 4);
        Ts[tr][dc4 * 4 + 0] = v.x; Ts[tr][dc4 * 4 + 1] = v.y;
        Ts[tr][dc4 * 4 + 2] = v.z; Ts[tr][dc4 * 4 + 3] = v.w;
    }
    __syncthreads();
    const int d = tid >> 2, tb = (tid & 3) * 16;
    #pragma unroll
    for (int p = 0; p < 4; ++p) {
        const int tq = tb + p * 4;
        ushort4 o;
        o.x = f2bf(Ts[tq + 0][d]); o.y = f2bf(Ts[tq + 1][d]);
        o.z = f2bf(Ts[tq + 2][d]); o.w = f2bf(Ts[tq + 3][d]);
        *(ushort4*)(Vt + (size_t)((b * 16 + h) * 64 + d) * 2048 + t0 + tq) = o;
    }
}

// ---------------------------------------------------------------------------
// MFMA GEMM (m97 structure): C = Xb(4096x1024) @ Wt^T + bias
//   128x128 tile, BK=32, unpadded LDS, global_load_lds width-16 staging.
//   Epilogue: +bias; Q gets *0.125 (attn scale folded); scatter [b,h,t,d].
// ---------------------------------------------------------------------------
__global__ __launch_bounds__(256) void gemm_kernel(
    const ush* __restrict__ Xb, const ush* __restrict__ Wt,
    const float* __restrict__ bias,
    ush* __restrict__ Qb, ush* __restrict__ Kb)
{
    __shared__ ush As[128 * 32];   // [m][k] unpadded (global_load_lds layout)
    __shared__ ush Bs[128 * 32];   // [n][k]

    const int tid = threadIdx.x;
    const int wid = tid >> 6, lane = tid & 63;
    const int quad = lane >> 4, l15 = lane & 15;
    const int wm = wid >> 1, wn = wid & 1;
    const int m0 = blockIdx.y * 128, n0 = blockIdx.x * 128;

    const int lrow = lane >> 2;        // 0..15
    const int lkk = (lane & 3) * 8;    // 0,8,16,24
    const size_t arow = (size_t)(m0 + wid * 32 + lrow);
    const size_t brow = (size_t)(n0 + wid * 32 + lrow);
    ush* AsW = &As[wid * 1024];        // wave-uniform LDS bases
    ush* BsW = &Bs[wid * 1024];

    f4v acc[4][4];
    #pragma unroll
    for (int i = 0; i < 4; ++i)
        #pragma unroll
        for (int j = 0; j < 4; ++j) acc[i][j] = (f4v){0.f, 0.f, 0.f, 0.f};

    for (int k0 = 0; k0 < 1024; k0 += 32) {
        gl_lds16(Xb + arow * 1024 + k0 + lkk, AsW);
        gl_lds16(Xb + (arow + 16) * 1024 + k0 + lkk, AsW + 512);
        gl_lds16(Wt + brow * 1024 + k0 + lkk, BsW);
        gl_lds16(Wt + (brow + 16) * 1024 + k0 + lkk, BsW + 512);
        __syncthreads();

        s8v a[4], bf[4];
        #pragma unroll
        for (int i = 0; i < 4; ++i)
            a[i] = *(const s8v*)&As[(wm * 64 + i * 16 + l15) * 32 + quad * 8];
        #pragma unroll
        for (int j = 0; j < 4; ++j)
            bf[j] = *(const s8v*)&Bs[(wn * 64 + j * 16 + l15) * 32 + quad * 8];
        #pragma unroll
        for (int i = 0; i < 4; ++i)
            #pragma unroll
            for (int j = 0; j < 4; ++j)
                acc[i][j] = __builtin_amdgcn_mfma_f32_16x16x32_bf16(
                    a[i], bf[j], acc[i][j], 0, 0, 0);
        __syncthreads();
    }

    // epilogue: C/D layout col=l15(n), row=quad*4+r(m)
    #pragma unroll
    for (int j = 0; j < 4; ++j) {
        const int n = n0 + wn * 64 + j * 16 + l15;
        const float bv = bias[n];
        const bool is_k = n >= 1024;
        const int nn = n & 1023;
        const int h = nn >> 6, d = nn & 63;
        ush* dst = is_k ? Kb : Qb;
        #pragma unroll
        for (int i = 0; i < 4; ++i) {
            const int mrow = m0 + wm * 64 + i * 16 + quad * 4;
            #pragma unroll
            for (int r = 0; r < 4; ++r) {
                const int m = mrow + r;
                const int b = m >> 11, t = m & 2047;
                float val = acc[i][j][r] + bv;
                if (!is_k) val *= 0.125f;     // fold 1/sqrt(D) into Q
                dst[(size_t)((b * 16 + h) * 2048 + t) * 64 + d] = f2bf(val);
            }
        }
    }
}

// ---------------------------------------------------------------------------
// MFMA causal flash attention, S^T formulation.
//   grid (32 bh, 32 qt-rev), 256 thr = 4 waves; wave w owns 16 q rows.
//   S^T = K·Q^T  ->  lane owns softmax row q=l15 (reductions = 2 shuffles).
//   P: 4x ds_write_b64 packed bf16 -> A-frag b128 reads (wave-private, Qs alias).
//   K/V: register-prefetch double staging (latency hidden behind compute).
// ---------------------------------------------------------------------------
__global__ __launch_bounds__(256) void attn_kernel(
    const ush* __restrict__ Qb, const ush* __restrict__ Kb,
    const ush* __restrict__ Vt, float* __restrict__ Y)
{
    __shared__ ush Qs[64 * 72];   // Q tile; reused as P after frag load
    __shared__ ush Ks[64 * 72];   // [key][d]
    __shared__ ush Vs[64 * 72];   // [d][key]

    const int tid = threadIdx.x;
    const int w = tid >> 6, lane = tid & 63;
    const int quad = lane >> 4, l15 = lane & 15;
    const int bh = blockIdx.x;
    const int b = bh >> 4, h = bh & 15;
    const int qt = gridDim.y - 1 - blockIdx.y;   // heavy tiles dispatch first
    const int q0 = qt * 64;

    const ush* Qg = Qb + (size_t)bh * 2048 * 64;
    const ush* Kg = Kb + (size_t)bh * 2048 * 64;
    const ush* Vg = Vt + (size_t)bh * 64 * 2048;

    const int srow = tid >> 3;      // 0..31
    const int sc = (tid & 7) * 8;   // elem offset, 16B chunks

    // Q tile + K/V tile 0 -> LDS (via regs)
    {
        uint4 qa = *(const uint4*)(Qg + (size_t)(q0 + srow) * 64 + sc);
        uint4 qb2 = *(const uint4*)(Qg + (size_t)(q0 + srow + 32) * 64 + sc);
        uint4 ka = *(const uint4*)(Kg + (size_t)srow * 64 + sc);
        uint4 kb2 = *(const uint4*)(Kg + (size_t)(srow + 32) * 64 + sc);
        uint4 va = *(const uint4*)(Vg + (size_t)srow * 2048 + sc);
        uint4 vb = *(const uint4*)(Vg + (size_t)(srow + 32) * 2048 + sc);
        *(uint4*)&Qs[srow * 72 + sc] = qa;
        *(uint4*)&Qs[(srow + 32) * 72 + sc] = qb2;
        *(uint4*)&Ks[srow * 72 + sc] = ka;
        *(uint4*)&Ks[(srow + 32) * 72 + sc] = kb2;
        *(uint4*)&Vs[srow * 72 + sc] = va;
        *(uint4*)&Vs[(srow + 32) * 72 + sc] = vb;
    }
    __syncthreads();

    s8v bq[2];   // Q as MFMA B-operand: lane l15 = q row (within wave's 16)
    #pragma unroll
    for (int s = 0; s < 2; ++s)
        bq[s] = *(const s8v*)&Qs[(w * 16 + l15) * 72 + s * 32 + quad * 8];
    __syncthreads();   // all Qs frag reads done -> Ps may overwrite Qs

    ush* Psw = &Qs[w * 16 * 72];   // wave-private P region: rows q=l15

    f4v acco[4];
    #pragma unroll
    for (int e = 0; e < 4; ++e) acco[e] = (f4v){0.f, 0.f, 0.f, 0.f};
    float mr = -INFINITY, lr = 0.f;

    for (int kt = 0; kt <= qt; ++kt) {
        const bool pf = kt < qt;
        uint4 ka, kb2, va, vb;
        if (pf) {   // prefetch next K/V tile into regs (latency overlapped)
            const int kn = (kt + 1) * 64;
            ka = *(const uint4*)(Kg + (size_t)(kn + srow) * 64 + sc);
            kb2 = *(const uint4*)(Kg + (size_t)(kn + srow + 32) * 64 + sc);
            va = *(const uint4*)(Vg + (size_t)srow * 2048 + kn + sc);
            vb = *(const uint4*)(Vg + (size_t)(srow + 32) * 2048 + kn + sc);
        }

        // S^T = K Q^T: D[key=quad*4+r (tile j)][q=l15]
        f4v sacc[4];
        #pragma unroll
        for (int j = 0; j < 4; ++j) sacc[j] = (f4v){0.f, 0.f, 0.f, 0.f};
        #pragma unroll
        for (int s = 0; s < 2; ++s) {
            #pragma unroll
            for (int j = 0; j < 4; ++j) {
                s8v ak = *(const s8v*)&Ks[(j * 16 + l15) * 72 + s * 32 + quad * 8];
                sacc[j] = __builtin_amdgcn_mfma_f32_16x16x32_bf16(
                    ak, bq[s], sacc[j], 0, 0, 0);
            }
        }

        float sv[4][4];
        #pragma unroll
        for (int j = 0; j < 4; ++j)
            #pragma unroll
            for (int r = 0; r < 4; ++r) sv[j][r] = sacc[j][r];
        if (kt == qt) {   // causal mask, diagonal tile only
            #pragma unroll
            for (int j = 0; j < 4; ++j)
                #pragma unroll
                for (int r = 0; r < 4; ++r)
                    if (j * 16 + quad * 4 + r > w * 16 + l15)
                        sv[j][r] = -INFINITY;
        }

        // online softmax; lane owns row q=l15 (replicated over 4 quads)
        float mloc = sv[0][0];
        #pragma unroll
        for (int j = 0; j < 4; ++j)
            #pragma unroll
            for (int r = 0; r < 4; ++r) mloc = fmaxf(mloc, sv[j][r]);
        mloc = fmaxf(mloc, __shfl_xor(mloc, 16));
        mloc = fmaxf(mloc, __shfl_xor(mloc, 32));
        const float mnew = fmaxf(mr, mloc);
        const float alpha = __expf(mr - mnew);
        mr = mnew;

        float pe[4][4], ps = 0.f;
        #pragma unroll
        for (int j = 0; j < 4; ++j)
            #pragma unroll
            for (int r = 0; r < 4; ++r) {
                pe[j][r] = __expf(sv[j][r] - mnew);
                ps += pe[j][r];
            }
        ps += __shfl_xor(ps, 16);
        ps += __shfl_xor(ps, 32);
        lr = lr * alpha + ps;

        // P -> LDS: lane's 4 values per tile j are consecutive keys
        #pragma unroll
        for (int j = 0; j < 4; ++j) {
            uint2 pk;
            pk.x = bfpack(pe[j][0], pe[j][1]);
            pk.y = bfpack(pe[j][2], pe[j][3]);
            *(uint2*)&Psw[l15 * 72 + j * 16 + quad * 4] = pk;
        }

        // rescale O (alpha of row quad*4+r via width-16 shuffle)
        #pragma unroll
        for (int r = 0; r < 4; ++r) {
            const float av = __shfl(alpha, quad * 4 + r, 16);
            #pragma unroll
            for (int e = 0; e < 4; ++e) acco[e][r] *= av;
        }

        // O += P @ V : A=P[q][key] (rows q=l15), B=Vs[d][key]
        #pragma unroll
        for (int s = 0; s < 2; ++s) {
            s8v ap = *(const s8v*)&Psw[l15 * 72 + s * 32 + quad * 8];
            #pragma unroll
            for (int e = 0; e < 4; ++e) {
                s8v bv = *(const s8v*)&Vs[(e * 16 + l15) * 72 + s * 32 + quad * 8];
                acco[e] = __builtin_amdgcn_mfma_f32_16x16x32_bf16(
                    ap, bv, acco[e], 0, 0, 0);
            }
        }

        __syncthreads();          // all waves done reading Ks/Vs
        if (pf) {
            *(uint4*)&Ks[srow * 72 + sc] = ka;
            *(uint4*)&Ks[(srow + 32) * 72 + sc] = kb2;
            *(uint4*)&Vs[srow * 72 + sc] = va;
            *(uint4*)&Vs[(srow + 32) * 72 + sc] = vb;
            __syncthreads();      // next tile staged
        }
    }

    // epilogue: O[q][d] row q=quad*4+r, col d=e*16+l15
    #pragma unroll
    for (int r = 0; r < 4; ++r) {
        const float lv = __shfl(lr, quad * 4 + r, 16);
        const float inv = 1.0f / lv;
        const int q = q0 + w * 16 + quad * 4 + r;
        #pragma unroll
        for (int e = 0; e < 4; ++e) {
            const int d = e * 16 + l15;
            Y[(size_t)(b * 2048 + q) * 1024 + h * 64 + d] = acco[e][r] * inv;
        }
    }
}

// ---------------------------------------------------------------------------
extern "C" void kernel_launch(void* const* d_in, const int* in_sizes, int n_in,
                              void* d_out, int out_size, void* d_ws,
                              size_t ws_size, hipStream_t stream)
{
    const float* x_qk = (const float*)d_in[0];
    const float* x_v  = (const float*)d_in[1];
    const float* W    = (const float*)d_in[2];
    const float* bias = (const float*)d_in[3];
    float* out = (float*)d_out;

    unsigned char* ws = (unsigned char*)d_ws;
    // Peak usage 28 MB (<= 33.5 MB proven available in R2).
    // Xb dead after gemm; Vt overlays it (vt runs after gemm).
    ush* Xb = (ush*)(ws);                  // 8 MB  [0,8M)
    ush* Vt = (ush*)(ws);                  // 8 MB  [0,8M)  (after gemm)
    ush* Wt = (ush*)(ws + (8u << 20));     // 4 MB  [8M,12M)
    ush* Qb = (ush*)(ws + (12u << 20));    // 8 MB  [12M,20M)
    ush* Kb = (ush*)(ws + (20u << 20));    // 8 MB  [20M,28M)

    xb_kernel<<<2048, 256, 0, stream>>>(x_qk, Xb);
    wt_kernel<<<dim3(32, 16), 256, 0, stream>>>(W, Wt);
    gemm_kernel<<<dim3(16, 32), 256, 0, stream>>>(Xb, Wt, bias, Qb, Kb);
    vt_kernel<<<dim3(32, 32), 256, 0, stream>>>(x_v, Vt);
    attn_kernel<<<dim3(32, 32), 256, 0, stream>>>(Qb, Kb, Vt, out);
}

// Round 5
// 162.530 us; speedup vs baseline: 6.5421x; 1.0250x over previous
//
#include <hip/hip_runtime.h>
#include <hip/hip_bf16.h>
#include <math.h>

// B=2, T=2048, C=1024, H=16, D=64
typedef __attribute__((ext_vector_type(8))) short s8v;    // 8 bf16
typedef __attribute__((ext_vector_type(4))) float f4v;    // 4 fp32
typedef __attribute__((ext_vector_type(16))) float f16v;  // 16 fp32 (32x32 C/D)
typedef unsigned short ush;
typedef unsigned int u32;

#define QSCALE 0.180336880f   /* 0.125 * log2(e): S emerges in log2 domain */

static __device__ __forceinline__ ush f2bf(float f) {
    u32 x = __builtin_bit_cast(u32, f);
    return (ush)((x + 0x7fffu + ((x >> 16) & 1u)) >> 16);
}
static __device__ __forceinline__ u32 bfpack(float lo, float hi) {
    u32 a = __builtin_bit_cast(u32, lo) + 0x8000u;
    u32 b = __builtin_bit_cast(u32, hi) + 0x8000u;
    return __builtin_amdgcn_perm(b, a, 0x07060302);
}
static __device__ __forceinline__ void gl_lds16(const void* g, void* l) {
    __builtin_amdgcn_global_load_lds(
        (const __attribute__((address_space(1))) u32*)g,
        (__attribute__((address_space(3))) u32*)l, 16, 0, 0);
}
#if __has_builtin(__builtin_amdgcn_exp2f)
#define EXP2F(x) __builtin_amdgcn_exp2f(x)
#else
#define EXP2F(x) exp2f(x)
#endif

// ---------------------------------------------------------------------------
// Prep A (fused): blocks [0,2048): Xb = bf16(X); [2048,2560): Wt[n][k]=W[k][n]
// ---------------------------------------------------------------------------
__global__ __launch_bounds__(256) void prepA_kernel(
    const float* __restrict__ X, const float* __restrict__ W,
    ush* __restrict__ Xb, ush* __restrict__ Wt)
{
    __shared__ float Ts[64][68];
    const int tid = threadIdx.x;
    const int bid = blockIdx.x;
    if (bid < 2048) {
        const size_t i = ((size_t)bid * 256 + tid) * 8;
        float4 v0 = *(const float4*)(X + i);
        float4 v1 = *(const float4*)(X + i + 4);
        uint4 o;
        o.x = bfpack(v0.x, v0.y); o.y = bfpack(v0.z, v0.w);
        o.z = bfpack(v1.x, v1.y); o.w = bfpack(v1.z, v1.w);
        *(uint4*)(Xb + i) = o;
    } else {
        const int id = bid - 2048;           // 512 blocks: 32 x 16
        const int n0 = (id & 31) * 64, k0 = (id >> 5) * 64;
        #pragma unroll
        for (int p = 0; p < 4; ++p) {
            const int idx = p * 256 + tid;
            const int kr = idx >> 4, nc4 = idx & 15;
            float4 v = *(const float4*)(W + (size_t)(k0 + kr) * 2048 + n0 + nc4 * 4);
            Ts[kr][nc4 * 4 + 0] = v.x; Ts[kr][nc4 * 4 + 1] = v.y;
            Ts[kr][nc4 * 4 + 2] = v.z; Ts[kr][nc4 * 4 + 3] = v.w;
        }
        __syncthreads();
        const int n = tid >> 2, kb = (tid & 3) * 16;
        #pragma unroll
        for (int p = 0; p < 4; ++p) {
            const int k = kb + p * 4;
            ushort4 o;
            o.x = f2bf(Ts[k + 0][n]); o.y = f2bf(Ts[k + 1][n]);
            o.z = f2bf(Ts[k + 2][n]); o.w = f2bf(Ts[k + 3][n]);
            *(ushort4*)(Wt + (size_t)(n0 + n) * 1024 + k0 + k) = o;
        }
    }
}

// ---------------------------------------------------------------------------
// Prep B: Vt[b][h][d][t] = bf16(x_v[b][t][h*64+d]).  grid (32, 32).
// (runs after gemm so Vt may overlay Xb in the workspace)
// ---------------------------------------------------------------------------
__global__ __launch_bounds__(256) void vt_kernel(
    const float* __restrict__ XV, ush* __restrict__ Vt)
{
    __shared__ float Ts[64][68];
    const int tid = threadIdx.x;
    const int t0 = blockIdx.x * 64;
    const int bh = blockIdx.y;
    const int b = bh >> 4, h = bh & 15;
    #pragma unroll
    for (int p = 0; p < 4; ++p) {
        const int idx = p * 256 + tid;
        const int tr = idx >> 4, dc4 = idx & 15;
        float4 v = *(const float4*)(XV + (size_t)(b * 2048 + t0 + tr) * 1024
                                    + h * 64 + dc4 * 4);
        Ts[tr][dc4 * 4 + 0] = v.x; Ts[tr][dc4 * 4 + 1] = v.y;
        Ts[tr][dc4 * 4 + 2] = v.z; Ts[tr][dc4 * 4 + 3] = v.w;
    }
    __syncthreads();
    const int d = tid >> 2, tb = (tid & 3) * 16;
    #pragma unroll
    for (int p = 0; p < 4; ++p) {
        const int tq = tb + p * 4;
        ushort4 o;
        o.x = f2bf(Ts[tq + 0][d]); o.y = f2bf(Ts[tq + 1][d]);
        o.z = f2bf(Ts[tq + 2][d]); o.w = f2bf(Ts[tq + 3][d]);
        *(ushort4*)(Vt + (size_t)((b * 16 + h) * 64 + d) * 2048 + t0 + tq) = o;
    }
}

// ---------------------------------------------------------------------------
// MFMA GEMM (m97 structure): C = Xb @ Wt^T + bias; Q scaled by 0.125*log2e.
// ---------------------------------------------------------------------------
__global__ __launch_bounds__(256) void gemm_kernel(
    const ush* __restrict__ Xb, const ush* __restrict__ Wt,
    const float* __restrict__ bias,
    ush* __restrict__ Qb, ush* __restrict__ Kb)
{
    __shared__ ush As[128 * 32];
    __shared__ ush Bs[128 * 32];

    const int tid = threadIdx.x;
    const int wid = tid >> 6, lane = tid & 63;
    const int quad = lane >> 4, l15 = lane & 15;
    const int wm = wid >> 1, wn = wid & 1;
    const int m0 = blockIdx.y * 128, n0 = blockIdx.x * 128;

    const int lrow = lane >> 2;
    const int lkk = (lane & 3) * 8;
    const size_t arow = (size_t)(m0 + wid * 32 + lrow);
    const size_t brow = (size_t)(n0 + wid * 32 + lrow);
    ush* AsW = &As[wid * 1024];
    ush* BsW = &Bs[wid * 1024];

    f4v acc[4][4];
    #pragma unroll
    for (int i = 0; i < 4; ++i)
        #pragma unroll
        for (int j = 0; j < 4; ++j) acc[i][j] = (f4v){0.f, 0.f, 0.f, 0.f};

    for (int k0 = 0; k0 < 1024; k0 += 32) {
        gl_lds16(Xb + arow * 1024 + k0 + lkk, AsW);
        gl_lds16(Xb + (arow + 16) * 1024 + k0 + lkk, AsW + 512);
        gl_lds16(Wt + brow * 1024 + k0 + lkk, BsW);
        gl_lds16(Wt + (brow + 16) * 1024 + k0 + lkk, BsW + 512);
        __syncthreads();

        s8v a[4], bf[4];
        #pragma unroll
        for (int i = 0; i < 4; ++i)
            a[i] = *(const s8v*)&As[(wm * 64 + i * 16 + l15) * 32 + quad * 8];
        #pragma unroll
        for (int j = 0; j < 4; ++j)
            bf[j] = *(const s8v*)&Bs[(wn * 64 + j * 16 + l15) * 32 + quad * 8];
        #pragma unroll
        for (int i = 0; i < 4; ++i)
            #pragma unroll
            for (int j = 0; j < 4; ++j)
                acc[i][j] = __builtin_amdgcn_mfma_f32_16x16x32_bf16(
                    a[i], bf[j], acc[i][j], 0, 0, 0);
        __syncthreads();
    }

    #pragma unroll
    for (int j = 0; j < 4; ++j) {
        const int n = n0 + wn * 64 + j * 16 + l15;
        const float bv = bias[n];
        const bool is_k = n >= 1024;
        const int nn = n & 1023;
        const int h = nn >> 6, d = nn & 63;
        ush* dst = is_k ? Kb : Qb;
        #pragma unroll
        for (int i = 0; i < 4; ++i) {
            const int mrow = m0 + wm * 64 + i * 16 + quad * 4;
            #pragma unroll
            for (int r = 0; r < 4; ++r) {
                const int m = mrow + r;
                const int b = m >> 11, t = m & 2047;
                float val = acc[i][j][r] + bv;
                if (!is_k) val *= QSCALE;
                dst[(size_t)((b * 16 + h) * 2048 + t) * 64 + d] = f2bf(val);
            }
        }
    }
}

// ---------------------------------------------------------------------------
// MFMA causal flash attention, 32x32x16, S^T form, 128 q-rows per block.
//   4 waves x 32 q. S^T = K·Q^T -> lane's column q = lane&31 (alpha is
//   lane-uniform: no shuffles for rescale). K/V staged by XOR-swizzled
//   global_load_lds, double-buffered. P/Q region per-wave (72-elem rows).
//   Epilogue via LDS transpose for coalesced stores.
// ---------------------------------------------------------------------------
__global__ __launch_bounds__(256, 2) void attn_kernel(
    const ush* __restrict__ Qb, const ush* __restrict__ Kb,
    const ush* __restrict__ Vt, float* __restrict__ Y)
{
    // SMEM carve: Kbuf 2x4096, Vbuf 2x4096, Pq 4x(32*72)  (51200 B total)
    __shared__ ush SMEM[25600];
    ush* Kbuf = SMEM;                 // [buf*4096 + row*64 + elem]
    ush* Vbuf = SMEM + 8192;
    ush* Pq   = SMEM + 16384;        // + w*2304

    const int tid = threadIdx.x;
    const int w = tid >> 6, lane = tid & 63;
    const int l31 = lane & 31, hi = lane >> 5;     // hi in {0,1}

    // block mapping: CU gets blocks i and i+256 with qt summing to 15
    const int idx = blockIdx.x;
    const int half = idx >> 8, pair = idx & 255;
    const int qt = half ? (pair & 15) : 15 - (pair & 15);
    const int bh = (pair >> 4) + half * 16;
    const int b = bh >> 4, h = bh & 15;
    const int q0 = qt * 128;
    const int ktmax = 2 * qt + 1;

    const ush* Qg = Qb + (size_t)bh * 2048 * 64;
    const ush* Kg = Kb + (size_t)bh * 2048 * 64;
    const ush* Vg = Vt + (size_t)bh * 64 * 2048;

    ush* Pw = Pq + w * 2304;

    // ---- stage Q rows (wave-private) and pull B-frags into regs
    {
        const int r8 = lane >> 3, c8 = lane & 7;
        #pragma unroll
        for (int p = 0; p < 4; ++p) {
            const int row = p * 8 + r8;
            uint4 v = *(const uint4*)(Qg + (size_t)(q0 + w * 32 + row) * 64 + c8 * 8);
            *(uint4*)&Pw[row * 72 + c8 * 8] = v;
        }
    }
    s8v bq[4];
    #pragma unroll
    for (int s = 0; s < 4; ++s)
        bq[s] = *(const s8v*)&Pw[l31 * 72 + s * 16 + hi * 8];

    // ---- swizzled DMA staging: chunk c of row r -> LDS chunk c^(r&7)
    const int r8 = lane >> 3;                 // 0..7
    const int g8 = ((lane & 7) ^ r8) * 8;     // swizzled global elem offset
    auto stage = [&](int kt, int buf) {
        const int k0e = kt * 64;
        const ush* kg = Kg + (size_t)(k0e + w * 16 + r8) * 64 + g8;
        gl_lds16(kg, &Kbuf[buf * 4096 + (w * 16) * 64]);
        gl_lds16(kg + 8 * 64, &Kbuf[buf * 4096 + (w * 16 + 8) * 64]);
        const ush* vg = Vg + (size_t)(w * 16 + r8) * 2048 + k0e + g8;
        gl_lds16(vg, &Vbuf[buf * 4096 + (w * 16) * 64]);
        gl_lds16(vg + 8 * 2048, &Vbuf[buf * 4096 + (w * 16 + 8) * 64]);
    };

    f16v acco0 = {}, acco1 = {};
    float mr = -INFINITY, lr = 0.f;
    const int qg = q0 + w * 32 + l31;         // this lane's q row (global)

    stage(0, 0);
    __syncthreads();                           // drains DMA (vmcnt before barrier)

    for (int kt = 0; kt <= ktmax; ++kt) {
        const int buf = kt & 1;
        if (kt < ktmax) stage(kt + 1, buf ^ 1);

        // S^T = K Q^T: rows=keys (2 tiles of 32), col=q=l31
        f16v s0 = {}, s1 = {};
        #pragma unroll
        for (int s = 0; s < 4; ++s) {
            const int ch = (s << 1) + hi;                 // k-chunk 0..7
            const int row0 = l31, row1 = 32 + l31;
            s8v ak0 = *(const s8v*)&Kbuf[buf * 4096 + row0 * 64 + ((ch ^ (row0 & 7)) << 3)];
            s8v ak1 = *(const s8v*)&Kbuf[buf * 4096 + row1 * 64 + ((ch ^ (row1 & 7)) << 3)];
            s0 = __builtin_amdgcn_mfma_f32_32x32x16_bf16(ak0, bq[s], s0, 0, 0, 0);
            s1 = __builtin_amdgcn_mfma_f32_32x32x16_bf16(ak1, bq[s], s1, 0, 0, 0);
        }

        // mask (diag region only) + running max
        const bool needmask = (kt * 64 + 63) > (q0 + w * 32);
        float mloc = -INFINITY;
        #pragma unroll
        for (int r = 0; r < 16; ++r) {
            float v0 = s0[r], v1 = s1[r];
            if (needmask) {
                const int keyb = kt * 64 + (r & 3) + 8 * (r >> 2) + 4 * hi;
                if (keyb > qg) v0 = -INFINITY;
                if (keyb + 32 > qg) v1 = -INFINITY;
                s0[r] = v0; s1[r] = v1;
            }
            mloc = fmaxf(mloc, fmaxf(v0, v1));
        }
        mloc = fmaxf(mloc, __shfl_xor(mloc, 32));
        const float mnew = fmaxf(mr, mloc);
        const float alpha = EXP2F(mr - mnew);   // kt=0: exp2(-inf)=0
        mr = mnew;

        // exp2, sum, pack P -> LDS ([q][key], 4 consecutive keys per b64)
        float ps = 0.f;
        #pragma unroll
        for (int g4 = 0; g4 < 4; ++g4) {
            float e0a = EXP2F(s0[g4 * 4 + 0] - mnew), e0b = EXP2F(s0[g4 * 4 + 1] - mnew);
            float e0c = EXP2F(s0[g4 * 4 + 2] - mnew), e0d = EXP2F(s0[g4 * 4 + 3] - mnew);
            float e1a = EXP2F(s1[g4 * 4 + 0] - mnew), e1b = EXP2F(s1[g4 * 4 + 1] - mnew);
            float e1c = EXP2F(s1[g4 * 4 + 2] - mnew), e1d = EXP2F(s1[g4 * 4 + 3] - mnew);
            ps += (e0a + e0b) + (e0c + e0d) + (e1a + e1b) + (e1c + e1d);
            uint2 p0; p0.x = bfpack(e0a, e0b); p0.y = bfpack(e0c, e0d);
            uint2 p1; p1.x = bfpack(e1a, e1b); p1.y = bfpack(e1c, e1d);
            const int off = g4 * 8 + hi * 4;
            *(uint2*)&Pw[l31 * 72 + off] = p0;
            *(uint2*)&Pw[l31 * 72 + 32 + off] = p1;
        }
        ps += __shfl_xor(ps, 32);
        lr = lr * alpha + ps;

        // rescale O (alpha lane-uniform!)
        #pragma unroll
        for (int r = 0; r < 16; ++r) { acco0[r] *= alpha; acco1[r] *= alpha; }

        // O^T += V^T P^T : rows=d (2 tiles of 32), col=q
        #pragma unroll
        for (int s = 0; s < 4; ++s) {
            s8v pf = *(const s8v*)&Pw[l31 * 72 + s * 16 + hi * 8];
            const int ch = (s << 1) + hi;
            const int row0 = l31, row1 = 32 + l31;
            s8v av0 = *(const s8v*)&Vbuf[buf * 4096 + row0 * 64 + ((ch ^ (row0 & 7)) << 3)];
            s8v av1 = *(const s8v*)&Vbuf[buf * 4096 + row1 * 64 + ((ch ^ (row1 & 7)) << 3)];
            acco0 = __builtin_amdgcn_mfma_f32_32x32x16_bf16(av0, pf, acco0, 0, 0, 0);
            acco1 = __builtin_amdgcn_mfma_f32_32x32x16_bf16(av1, pf, acco1, 0, 0, 0);
        }

        __syncthreads();   // waves done with buf; DMAs for buf^1 drained here
    }

    // ---- epilogue: LDS transpose (overlay K/V/P area) -> coalesced stores
    __syncthreads();
    float* LTw = (float*)SMEM + w * (32 * 68);
    const float inv = 1.0f / lr;
    #pragma unroll
    for (int r = 0; r < 16; ++r) {
        const int d = (r & 3) + 8 * (r >> 2) + 4 * hi;
        LTw[l31 * 68 + d] = acco0[r] * inv;
        LTw[l31 * 68 + 32 + d] = acco1[r] * inv;
    }
    // wave-private region; DS in-order. Read rows, store float4.
    const int qr4 = lane >> 4, chk = lane & 15;
    #pragma unroll
    for (int p = 0; p < 8; ++p) {
        const int qrow = p * 4 + qr4;
        f4v v = *(const f4v*)&LTw[qrow * 68 + chk * 4];
        *(float4*)(Y + (size_t)(b * 2048 + q0 + w * 32 + qrow) * 1024
                   + h * 64 + chk * 4) = (float4){v[0], v[1], v[2], v[3]};
    }
}

// ---------------------------------------------------------------------------
extern "C" void kernel_launch(void* const* d_in, const int* in_sizes, int n_in,
                              void* d_out, int out_size, void* d_ws,
                              size_t ws_size, hipStream_t stream)
{
    const float* x_qk = (const float*)d_in[0];
    const float* x_v  = (const float*)d_in[1];
    const float* W    = (const float*)d_in[2];
    const float* bias = (const float*)d_in[3];
    float* out = (float*)d_out;

    unsigned char* ws = (unsigned char*)d_ws;
    ush* Xb = (ush*)(ws);                  // 8 MB; dead after gemm
    ush* Vt = (ush*)(ws);                  // 8 MB; written after gemm
    ush* Wt = (ush*)(ws + (8u << 20));     // 4 MB
    ush* Qb = (ush*)(ws + (12u << 20));    // 8 MB
    ush* Kb = (ush*)(ws + (20u << 20));    // 8 MB (28 MB peak)

    prepA_kernel<<<2560, 256, 0, stream>>>(x_qk, W, Xb, Wt);
    gemm_kernel<<<dim3(16, 32), 256, 0, stream>>>(Xb, Wt, bias, Qb, Kb);
    vt_kernel<<<dim3(32, 32), 256, 0, stream>>>(x_v, Vt);
    attn_kernel<<<512, 256, 0, stream>>>(Qb, Kb, Vt, out);
}